// Round 1
// 709.351 us; speedup vs baseline: 1.0012x; 1.0012x over previous
//
#include <hip/hip_runtime.h>

#define NB 50          // bins
#define DD 512         // feature dim
#define KSZ 5
#define SORT_ROWS 4096     // rows per sort block
#define EPT 16             // elements per thread in sort (4096/256)
#define RPW 64             // rows per wave in reduce (64 divides SORT_ROWS)
#define UNR 8              // reduce inner unroll

typedef float f4 __attribute__((ext_vector_type(4)));

// ---------------------------------------------------------------------------
// Pass 0: block-local counting sort of labels. Each block owns 4096 rows and
// writes packed (row<<6)|lab entries, grouped by bin, into its own segment of
// `packed`. Also accumulates the global per-bin counts.
// ---------------------------------------------------------------------------
__global__ __launch_bounds__(256) void fds_sort(
    const int* __restrict__ labels,
    int*       __restrict__ packed,   // [N]
    float*     __restrict__ g_cnt)    // [NB]
{
    __shared__ int s_hist[NB];
    __shared__ int s_cur[NB];
    const int tid  = threadIdx.x;
    const int base = blockIdx.x * SORT_ROWS;

    if (tid < NB) s_hist[tid] = 0;
    __syncthreads();

    int lab[EPT];
#pragma unroll
    for (int j = 0; j < EPT; ++j) {
        lab[j] = labels[base + j * 256 + tid];          // coalesced
        __hip_atomic_fetch_add(&s_hist[lab[j]], 1,
                               __ATOMIC_RELAXED, __HIP_MEMORY_SCOPE_WORKGROUP);
    }
    __syncthreads();

    if (tid == 0) {
        int run = 0;
        for (int b = 0; b < NB; ++b) { s_cur[b] = run; run += s_hist[b]; }
    }
    __syncthreads();

    if (tid < NB)
        __hip_atomic_fetch_add(&g_cnt[tid], (float)s_hist[tid],
                               __ATOMIC_RELAXED, __HIP_MEMORY_SCOPE_AGENT);

#pragma unroll
    for (int j = 0; j < EPT; ++j) {
        const int l   = lab[j];
        const int pos = __hip_atomic_fetch_add(&s_cur[l], 1,
                              __ATOMIC_RELAXED, __HIP_MEMORY_SCOPE_WORKGROUP);
        const int row = base + j * 256 + tid;
        packed[base + pos] = (row << 6) | l;
    }
}

// ---------------------------------------------------------------------------
// Pass 1: gather-reduce over bin-grouped rows. One wave = 256 columns
// (float4 per lane) x 64 sorted rows. 1 KB contiguous per row per wave
// (vs 256 B before), 8 waves/SIMD occupancy (vs 4), accumulator in 8 VGPRs;
// flush to global fp atomics only when the (wave-uniform) label changes
// (~2x per wave). Feature loads are nontemporal (streamed once) so packed
// and g_sum/g_sq stay L2-resident.
// ---------------------------------------------------------------------------
__device__ __forceinline__ void flush4(
    float* __restrict__ g_sum, float* __restrict__ g_sq,
    int cur, int c0, f4 sum, f4 sq)
{
    float* ps = &g_sum[cur * DD + c0];
    float* pq = &g_sq [cur * DD + c0];
#pragma unroll
    for (int c = 0; c < 4; ++c) {
        __hip_atomic_fetch_add(ps + c, sum[c],
                               __ATOMIC_RELAXED, __HIP_MEMORY_SCOPE_AGENT);
        __hip_atomic_fetch_add(pq + c, sq[c],
                               __ATOMIC_RELAXED, __HIP_MEMORY_SCOPE_AGENT);
    }
}

__global__ __launch_bounds__(256) void fds_reduce(
    const float* __restrict__ features,
    const int*   __restrict__ packed,
    float* __restrict__ g_sum,
    float* __restrict__ g_sq)
{
    const int tid  = threadIdx.x;
    const int wave = tid >> 6;
    const int lane = tid & 63;
    const int gw   = blockIdx.x * 4 + wave;     // 0..8191
    const int cg2    = gw & 1;                  // column half (0..1)
    const int rchunk = gw >> 1;                 // 0..4095
    const int r0  = rchunk * RPW;
    const int c0  = cg2 * 256 + lane * 4;       // first of 4 columns
    const f4* __restrict__ f4p = (const f4*)features;  // 128 f4 per row

    f4 sum = (f4)0.f, sq = (f4)0.f;
    int cur = packed[r0] & 63;                  // uniform across wave

    int pk[UNR];
#pragma unroll
    for (int j = 0; j < UNR; ++j) pk[j] = packed[r0 + j];   // broadcast loads

    for (int it = 0; it < RPW; it += UNR) {
        // feature loads for current batch: 1 KB contiguous per row per wave
        f4 v[UNR];
#pragma unroll
        for (int j = 0; j < UNR; ++j)
            v[j] = __builtin_nontemporal_load(
                f4p + (size_t)(pk[j] >> 6) * (DD / 4) + cg2 * 64 + lane);

        // prefetch next batch of packed entries (breaks the dependent chain)
        int pk2[UNR];
        const int nb = (it + UNR < RPW) ? (r0 + it + UNR) : r0;
#pragma unroll
        for (int j = 0; j < UNR; ++j) pk2[j] = packed[nb + j];

#pragma unroll
        for (int j = 0; j < UNR; ++j) {
            const int l = pk[j] & 63;           // uniform
            if (l != cur) {                     // wave-coherent branch
                flush4(g_sum, g_sq, cur, c0, sum, sq);
                sum = (f4)0.f; sq = (f4)0.f; cur = l;
            }
            sum += v[j];
            sq  += v[j] * v[j];
        }
#pragma unroll
        for (int j = 0; j < UNR; ++j) pk[j] = pk2[j];
    }
    flush4(g_sum, g_sq, cur, c0, sum, sq);
}

// ---------------------------------------------------------------------------
// Pass 2: finalize (unchanged — verified correct).
// out layout: new_mean[25600] | new_var[25600] | new_num[50]
//             | smoothed_mean[25600] | smoothed_var[25600]
// ---------------------------------------------------------------------------
__global__ __launch_bounds__(256) void fds_finalize(
    const float* __restrict__ g_sum, const float* __restrict__ g_sq,
    const float* __restrict__ g_cnt,
    const float* __restrict__ running_mean, const float* __restrict__ running_var,
    const float* __restrict__ num_tracked, const float* __restrict__ kwin,
    float* __restrict__ out)
{
    __shared__ float s_cnt[NB];
    __shared__ float s_w[KSZ];
    const int tid = threadIdx.x;
    if (tid < NB)  s_cnt[tid] = g_cnt[tid];
    if (tid < KSZ) s_w[tid]   = kwin[tid];
    __syncthreads();

    const int idx = blockIdx.x * 256 + tid;   // 0..25599 (grid exactly 100)
    const int b = idx / DD;
    const int d = idx - b * DD;

    float sm = 0.f, sv = 0.f, my_nm = 0.f, my_nv = 0.f;
#pragma unroll
    for (int k = 0; k < KSZ; ++k) {
        const int i = b + k;
        const int bb = (i < 2) ? (2 - i) : ((i >= NB + 2) ? (2 * NB - i) : (i - 2));
        const float cnt    = s_cnt[bb];
        const float safe_n = fmaxf(cnt, 1.f);
        const float s   = g_sum[bb * DD + d];
        const float sqv = g_sq [bb * DD + d];
        const float mean = s / safe_n;
        const float var  = (sqv - safe_n * mean * mean) / fmaxf(cnt - 1.f, 1.f);
        const float rm = running_mean[bb * DD + d];
        const float rv = running_var [bb * DD + d];
        float nm, nv;
        if (cnt > 0.f) {
            nm = 0.1f * mean + 0.9f * rm;
            nv = 0.1f * var  + 0.9f * rv;
        } else {
            nm = rm; nv = rv;
        }
        sm += s_w[k] * nm;
        sv += s_w[k] * nv;
        if (k == 2) { my_nm = nm; my_nv = nv; }
    }
    out[idx]                    = my_nm;
    out[NB * DD + idx]          = my_nv;
    out[2 * NB * DD + NB + idx] = sm;
    out[3 * NB * DD + NB + idx] = sv;
    if (idx < NB)
        out[2 * NB * DD + idx] = num_tracked[idx] + s_cnt[idx];
}

extern "C" void kernel_launch(void* const* d_in, const int* in_sizes, int n_in,
                              void* d_out, int out_size, void* d_ws, size_t ws_size,
                              hipStream_t stream)
{
    const float* features     = (const float*)d_in[0];
    const int*   labels       = (const int*)  d_in[1];
    const float* running_mean = (const float*)d_in[2];
    const float* running_var  = (const float*)d_in[3];
    const float* num_tracked  = (const float*)d_in[4];
    const float* kwin         = (const float*)d_in[5];
    float* out = (float*)d_out;

    const int N = in_sizes[1];   // 262144 rows

    // ws layout: g_sum[25600] | g_sq[25600] | g_cnt[50] | packed[N]
    float* g_sum  = (float*)d_ws;
    float* g_sq   = g_sum + NB * DD;
    float* g_cnt  = g_sq  + NB * DD;
    int*   packed = (int*)(g_cnt + NB);

    hipMemsetAsync(d_ws, 0, (size_t)(2 * NB * DD + NB) * sizeof(float), stream);

    fds_sort<<<N / SORT_ROWS, 256, 0, stream>>>(labels, packed, g_cnt);

    // (N/RPW) chunks * 2 column halves, 4 waves per block
    fds_reduce<<<(N / RPW) * 2 / 4, 256, 0, stream>>>(features, packed, g_sum, g_sq);

    fds_finalize<<<NB * DD / 256, 256, 0, stream>>>(
        g_sum, g_sq, g_cnt, running_mean, running_var, num_tracked, kwin, out);
}

// Round 2
// 692.574 us; speedup vs baseline: 1.0254x; 1.0242x over previous
//
#include <hip/hip_runtime.h>

#define NB 50          // bins
#define DD 512         // feature dim
#define KSZ 5
#define SORT_ROWS 4096     // rows per sort block
#define EPT 16             // elements per thread in sort (4096/256)
#define UNR 8              // reduce inner unroll

typedef float f4 __attribute__((ext_vector_type(4)));

// ---------------------------------------------------------------------------
// Pass 0: block-local counting sort of labels. Each block owns 4096 rows and
// writes packed (row<<6)|lab entries, grouped by bin, into its own segment of
// `packed`. Exports the per-block bin start offsets (bofs, NB+1 entries per
// block) so the reduce can process exact bin segments without atomics.
// ---------------------------------------------------------------------------
__global__ __launch_bounds__(256) void fds_sort(
    const int* __restrict__ labels,
    int*       __restrict__ packed,   // [N]
    int*       __restrict__ bofs,     // [nblk][NB+1]
    float*     __restrict__ g_cnt)    // [NB]
{
    __shared__ int s_hist[NB];
    __shared__ int s_cur[NB];
    const int tid  = threadIdx.x;
    const int base = blockIdx.x * SORT_ROWS;

    if (tid < NB) s_hist[tid] = 0;
    __syncthreads();

    int lab[EPT];
#pragma unroll
    for (int j = 0; j < EPT; ++j) {
        lab[j] = labels[base + j * 256 + tid];          // coalesced
        __hip_atomic_fetch_add(&s_hist[lab[j]], 1,
                               __ATOMIC_RELAXED, __HIP_MEMORY_SCOPE_WORKGROUP);
    }
    __syncthreads();

    if (tid == 0) {
        int run = 0;
        for (int b = 0; b < NB; ++b) { s_cur[b] = run; run += s_hist[b]; }
    }
    __syncthreads();

    // export per-block segment offsets BEFORE the placement loop mutates s_cur
    if (tid < NB) {
        __hip_atomic_fetch_add(&g_cnt[tid], (float)s_hist[tid],
                               __ATOMIC_RELAXED, __HIP_MEMORY_SCOPE_AGENT);
        bofs[blockIdx.x * (NB + 1) + tid] = s_cur[tid];
    }
    if (tid == 0) bofs[blockIdx.x * (NB + 1) + NB] = SORT_ROWS;
    __syncthreads();   // offsets saved before any s_cur mutation

#pragma unroll
    for (int j = 0; j < EPT; ++j) {
        const int l   = lab[j];
        const int pos = __hip_atomic_fetch_add(&s_cur[l], 1,
                              __ATOMIC_RELAXED, __HIP_MEMORY_SCOPE_WORKGROUP);
        const int row = base + j * 256 + tid;
        packed[base + pos] = (row << 6) | l;
    }
}

// ---------------------------------------------------------------------------
// Pass 1: ATOMIC-FREE segmented reduce. One wave owns one
// (sort-block, bin, column-half): it accumulates exactly the rows of that
// bin segment (offsets from bofs) and writes its partial sums with plain
// float4 stores into an exclusively-owned slot of `part`.
// part layout: sum[nseg][DD] | sq[nseg][DD], nseg = nblk*NB.
// ---------------------------------------------------------------------------
__global__ __launch_bounds__(256) void fds_reduce(
    const float* __restrict__ features,
    const int*   __restrict__ packed,
    const int*   __restrict__ bofs,
    float*       __restrict__ part,
    int nseg)
{
    const int tid  = threadIdx.x;
    const int wave = tid >> 6;
    const int lane = tid & 63;
    const int gw   = blockIdx.x * 4 + wave;     // 0 .. nseg*2-1
    const int half = gw & 1;                    // column half
    const int seg  = gw >> 1;                   // 0 .. nseg-1
    const int blk  = seg / NB;
    const int bin  = seg - blk * NB;
    const int base = blk * SORT_ROWS;
    const int s    = bofs[blk * (NB + 1) + bin];
    const int e    = bofs[blk * (NB + 1) + bin + 1];
    const int c    = half * 64 + lane;          // f4 index within a row
    const f4* __restrict__ fp = (const f4*)features;   // DD/4 = 128 per row

    f4 sum = (f4)0.f, sq = (f4)0.f;
    for (int i0 = s; i0 < e; i0 += UNR) {
        const int n = e - i0;                   // >= 1, wave-uniform
        int pk[UNR];
#pragma unroll
        for (int j = 0; j < UNR; ++j)
            pk[j] = packed[base + i0 + (j < n ? j : 0)];   // clamped tail
        f4 v[UNR];
#pragma unroll
        for (int j = 0; j < UNR; ++j)
            v[j] = __builtin_nontemporal_load(
                fp + (size_t)(pk[j] >> 6) * (DD / 4) + c);
#pragma unroll
        for (int j = 0; j < UNR; ++j)
            if (j < n) { sum += v[j]; sq += v[j] * v[j]; }
    }

    f4* ps = (f4*)part;
    ps[(size_t)seg * (DD / 4) + c]          = sum;   // exclusive slot: no atomic
    ps[(size_t)(nseg + seg) * (DD / 4) + c] = sq;
}

// ---------------------------------------------------------------------------
// Pass 1.5: sum the nblk per-block partials into dense g_sum / g_sq.
// 25600 threads, fully coalesced; ~13 MB of L2/L3 traffic.
// ---------------------------------------------------------------------------
__global__ __launch_bounds__(256) void fds_partsum(
    const float* __restrict__ part, int nblk,
    float* __restrict__ g_sum, float* __restrict__ g_sq)
{
    const int idx = blockIdx.x * 256 + threadIdx.x;   // 0..25599
    const int bin = idx / DD;
    const int d   = idx - bin * DD;
    const int nseg = nblk * NB;
    float s = 0.f, q = 0.f;
#pragma unroll 4
    for (int blk = 0; blk < nblk; ++blk) {
        s += part[(size_t)(blk * NB + bin) * DD + d];
        q += part[(size_t)(nseg + blk * NB + bin) * DD + d];
    }
    g_sum[idx] = s;
    g_sq [idx] = q;
}

// ---------------------------------------------------------------------------
// Pass 2: finalize (unchanged — verified correct).
// out layout: new_mean[25600] | new_var[25600] | new_num[50]
//             | smoothed_mean[25600] | smoothed_var[25600]
// ---------------------------------------------------------------------------
__global__ __launch_bounds__(256) void fds_finalize(
    const float* __restrict__ g_sum, const float* __restrict__ g_sq,
    const float* __restrict__ g_cnt,
    const float* __restrict__ running_mean, const float* __restrict__ running_var,
    const float* __restrict__ num_tracked, const float* __restrict__ kwin,
    float* __restrict__ out)
{
    __shared__ float s_cnt[NB];
    __shared__ float s_w[KSZ];
    const int tid = threadIdx.x;
    if (tid < NB)  s_cnt[tid] = g_cnt[tid];
    if (tid < KSZ) s_w[tid]   = kwin[tid];
    __syncthreads();

    const int idx = blockIdx.x * 256 + tid;   // 0..25599 (grid exactly 100)
    const int b = idx / DD;
    const int d = idx - b * DD;

    float sm = 0.f, sv = 0.f, my_nm = 0.f, my_nv = 0.f;
#pragma unroll
    for (int k = 0; k < KSZ; ++k) {
        const int i = b + k;
        const int bb = (i < 2) ? (2 - i) : ((i >= NB + 2) ? (2 * NB - i) : (i - 2));
        const float cnt    = s_cnt[bb];
        const float safe_n = fmaxf(cnt, 1.f);
        const float s   = g_sum[bb * DD + d];
        const float sqv = g_sq [bb * DD + d];
        const float mean = s / safe_n;
        const float var  = (sqv - safe_n * mean * mean) / fmaxf(cnt - 1.f, 1.f);
        const float rm = running_mean[bb * DD + d];
        const float rv = running_var [bb * DD + d];
        float nm, nv;
        if (cnt > 0.f) {
            nm = 0.1f * mean + 0.9f * rm;
            nv = 0.1f * var  + 0.9f * rv;
        } else {
            nm = rm; nv = rv;
        }
        sm += s_w[k] * nm;
        sv += s_w[k] * nv;
        if (k == 2) { my_nm = nm; my_nv = nv; }
    }
    out[idx]                    = my_nm;
    out[NB * DD + idx]          = my_nv;
    out[2 * NB * DD + NB + idx] = sm;
    out[3 * NB * DD + NB + idx] = sv;
    if (idx < NB)
        out[2 * NB * DD + idx] = num_tracked[idx] + s_cnt[idx];
}

extern "C" void kernel_launch(void* const* d_in, const int* in_sizes, int n_in,
                              void* d_out, int out_size, void* d_ws, size_t ws_size,
                              hipStream_t stream)
{
    const float* features     = (const float*)d_in[0];
    const int*   labels       = (const int*)  d_in[1];
    const float* running_mean = (const float*)d_in[2];
    const float* running_var  = (const float*)d_in[3];
    const float* num_tracked  = (const float*)d_in[4];
    const float* kwin         = (const float*)d_in[5];
    float* out = (float*)d_out;

    const int N    = in_sizes[1];        // 262144 rows
    const int nblk = N / SORT_ROWS;      // 64
    const int nseg = nblk * NB;          // 3200

    // ws layout: g_sum[25600] | g_sq[25600] | g_cnt[50] | packed[N]
    //            | bofs[nblk*(NB+1)] | (16B-aligned) part[2*nseg*DD]
    float* g_sum  = (float*)d_ws;
    float* g_sq   = g_sum + NB * DD;
    float* g_cnt  = g_sq  + NB * DD;
    int*   packed = (int*)(g_cnt + NB);
    int*   bofs   = packed + N;
    size_t off    = ((size_t)((char*)(bofs + nblk * (NB + 1)) - (char*)d_ws) + 15)
                    & ~(size_t)15;
    float* part   = (float*)((char*)d_ws + off);

    // only g_cnt accumulates via atomics; everything else is fully overwritten
    hipMemsetAsync(g_cnt, 0, NB * sizeof(float), stream);

    fds_sort<<<nblk, 256, 0, stream>>>(labels, packed, bofs, g_cnt);

    // one wave per (sort-block, bin, column-half): nseg*2 waves, 4 per block
    fds_reduce<<<nseg * 2 / 4, 256, 0, stream>>>(features, packed, bofs, part, nseg);

    fds_partsum<<<NB * DD / 256, 256, 0, stream>>>(part, nblk, g_sum, g_sq);

    fds_finalize<<<NB * DD / 256, 256, 0, stream>>>(
        g_sum, g_sq, g_cnt, running_mean, running_var, num_tracked, kwin, out);
}